// Round 10
// baseline (527.623 us; speedup 1.0000x reference)
//
#include <hip/hip_runtime.h>
#include <hip/hip_bf16.h>

#define H 4
#define D 256
#define NEG_SLOPE 0.2f

typedef __attribute__((ext_vector_type(8))) _Float16 f16x8;
typedef __attribute__((ext_vector_type(4))) _Float16 f16x4;
typedef __attribute__((ext_vector_type(4))) float f32x4;

// ---- merged f32->f16 convert: x[N,128] + W0[128*256] + W1..4[256*256] ----
__global__ void k_cvt_all(const float* __restrict__ x,
                          const float* __restrict__ w0, const float* __restrict__ w1,
                          const float* __restrict__ w2, const float* __restrict__ w3,
                          const float* __restrict__ w4,
                          _Float16* __restrict__ xf, _Float16* __restrict__ wf,
                          int nx4) {
    int i = blockIdx.x * blockDim.x + threadIdx.x;
    const int nW0 = 128 * 256 / 4, nW = 256 * 256 / 4;
    const float* src;
    _Float16* dst;
    int off;
    if (i < nx4) { src = x; dst = xf; off = i; }
    else {
        i -= nx4;
        if (i < nW0) { src = w0; dst = wf; off = i; }
        else {
            i -= nW0;
            int l = i / nW, r2 = i % nW;
            if (l >= 4) return;
            const float* ws[4] = {w1, w2, w3, w4};
            src = ws[l];
            dst = wf + 128 * 256 + (size_t)l * 256 * 256;
            off = r2;
        }
    }
    float4 v = ((const float4*)src)[off];
    f16x4 o = {(_Float16)v.x, (_Float16)v.y, (_Float16)v.z, (_Float16)v.w};
    *(f16x4*)&dst[(size_t)off * 4] = o;
}

// ---- MFMA GEMM v2: BK=64, register-staged prefetch, fused alpha ----
// grid = ceil(N/64) x 256 thr (4 waves). Wave w: rows w*16..+15, all 256 cols.
template<int K>
__global__ __launch_bounds__(256) void k_gemm_mfma(
        const _Float16* __restrict__ xf, const _Float16* __restrict__ wf,
        const float* __restrict__ att_src, const float* __restrict__ att_dst,
        _Float16* __restrict__ hmat, float* __restrict__ alpha_src,
        float* __restrict__ alpha_dst, int nrows) {
    const int NSTEP = K / 64;
    __shared__ _Float16 sx[64][72];     // pad 64->72 (144B rows)
    __shared__ _Float16 sw[256][72];
    int t = threadIdx.x;
    int w = t >> 6, l = t & 63;
    int r = l & 15, q = l >> 4;
    int row0 = blockIdx.x * 64;
    int srow = t >> 2;                  // staging row 0..63
    int scol = (t & 3) * 16;            // staging col base within BK
    int gxr  = row0 + srow;
    bool xok = (gxr < nrows);

    f32x4 acc[16];
    #pragma unroll
    for (int cf = 0; cf < 16; ++cf) acc[cf] = (f32x4){0.f, 0.f, 0.f, 0.f};

    // prologue: load step 0 into regs
    uint4 ldx[2], ldw[8];
    #pragma unroll
    for (int u = 0; u < 2; ++u)
        ldx[u] = xok ? *(const uint4*)&xf[(size_t)gxr * K + scol + u * 8]
                     : make_uint4(0, 0, 0, 0);
    #pragma unroll
    for (int i = 0; i < 4; ++i)
        #pragma unroll
        for (int u = 0; u < 2; ++u)
            ldw[i * 2 + u] = *(const uint4*)&wf[(size_t)(srow + i * 64) * K + scol + u * 8];

    for (int step = 0; step < NSTEP; ++step) {
        __syncthreads();               // prev-step LDS reads complete
        #pragma unroll
        for (int u = 0; u < 2; ++u)
            *(uint4*)&sx[srow][scol + u * 8] = ldx[u];
        #pragma unroll
        for (int i = 0; i < 4; ++i)
            #pragma unroll
            for (int u = 0; u < 2; ++u)
                *(uint4*)&sw[srow + i * 64][scol + u * 8] = ldw[i * 2 + u];
        // issue next step's global loads (latency hides under MFMA phase)
        if (step + 1 < NSTEP) {
            int k0 = (step + 1) * 64;
            #pragma unroll
            for (int u = 0; u < 2; ++u)
                ldx[u] = xok ? *(const uint4*)&xf[(size_t)gxr * K + k0 + scol + u * 8]
                             : make_uint4(0, 0, 0, 0);
            #pragma unroll
            for (int i = 0; i < 4; ++i)
                #pragma unroll
                for (int u = 0; u < 2; ++u)
                    ldw[i * 2 + u] = *(const uint4*)&wf[(size_t)(srow + i * 64) * K + k0 + scol + u * 8];
        }
        __syncthreads();               // LDS tile ready
        #pragma unroll
        for (int kk = 0; kk < 2; ++kk) {
            f16x8 a = *(f16x8*)&sx[w * 16 + r][kk * 32 + q * 8];
            #pragma unroll
            for (int cf = 0; cf < 16; ++cf) {
                f16x8 b = *(f16x8*)&sw[cf * 16 + r][kk * 32 + q * 8];
                acc[cf] = __builtin_amdgcn_mfma_f32_16x16x32_f16(a, b, acc[cf], 0, 0, 0);
            }
        }
    }
    // store h (fp16): D[row=(q*4+i)][col=cf*16+r]
    #pragma unroll
    for (int cf = 0; cf < 16; ++cf) {
        #pragma unroll
        for (int i = 0; i < 4; ++i) {
            int gr = row0 + w * 16 + q * 4 + i;
            if (gr < nrows) hmat[(size_t)gr * D + cf * 16 + r] = (_Float16)acc[cf][i];
        }
    }
    // fused alpha epilogue -> [node*4 + head]
    float asv[16], adv[16];
    #pragma unroll
    for (int cf = 0; cf < 16; ++cf) {
        asv[cf] = att_src[cf * 16 + r];
        adv[cf] = att_dst[cf * 16 + r];
    }
    #pragma unroll
    for (int i = 0; i < 4; ++i) {
        #pragma unroll
        for (int h4 = 0; h4 < 4; ++h4) {
            float ps = 0.f, pd = 0.f;
            #pragma unroll
            for (int j = 0; j < 4; ++j) {
                int cf = h4 * 4 + j;
                ps += acc[cf][i] * asv[cf];
                pd += acc[cf][i] * adv[cf];
            }
            #pragma unroll
            for (int m = 1; m < 16; m <<= 1) {
                ps += __shfl_xor(ps, m);
                pd += __shfl_xor(pd, m);
            }
            int gr = row0 + w * 16 + q * 4 + i;
            if (r == 0 && gr < nrows) {
                alpha_src[gr * 4 + h4] = ps;
                alpha_dst[gr * 4 + h4] = pd;
            }
        }
    }
}

// ---------------- CSR build (graph constant across layers) ----------------
__global__ void k_deg(const int* __restrict__ ei, int E, int E2, int* __restrict__ deg) {
    int e = blockIdx.x * blockDim.x + threadIdx.x;
    if (e >= E2) return;
    int de = (e < E) ? ei[E + e] : (e - E);
    atomicAdd(&deg[de], 1);
}

__global__ void k_scan_block(const int* __restrict__ deg, int* __restrict__ incl,
                             int* __restrict__ bsum, int n) {
    __shared__ int sd[256];
    int t = threadIdx.x;
    int i = blockIdx.x * 256 + t;
    int v = (i < n) ? deg[i] : 0;
    sd[t] = v;
    __syncthreads();
    for (int off = 1; off < 256; off <<= 1) {
        int add = (t >= off) ? sd[t - off] : 0;
        __syncthreads();
        sd[t] += add;
        __syncthreads();
    }
    if (i < n) incl[i] = sd[t];
    if (t == 255) bsum[blockIdx.x] = sd[255];
}

__global__ void k_scan_bsum(int* __restrict__ bsum, int nb) {
    __shared__ int sd[256];
    int t = threadIdx.x;
    int v = (t < nb) ? bsum[t] : 0;
    sd[t] = v;
    __syncthreads();
    for (int off = 1; off < 256; off <<= 1) {
        int add = (t >= off) ? sd[t - off] : 0;
        __syncthreads();
        sd[t] += add;
        __syncthreads();
    }
    if (t < nb) bsum[t] = sd[t] - v;
}

__global__ void k_rowptr(const int* __restrict__ incl, const int* __restrict__ deg,
                         const int* __restrict__ boff, int* __restrict__ row_ptr,
                         int n, int total) {
    int i = blockIdx.x * blockDim.x + threadIdx.x;
    if (i < n) row_ptr[i] = incl[i] - deg[i] + boff[i >> 8];
    if (i == 0) row_ptr[n] = total;
}

__global__ void k_scatter(const int* __restrict__ ei, int E, int E2,
                          const int* __restrict__ row_ptr, int* __restrict__ cursor,
                          int* __restrict__ csr_src) {
    int e = blockIdx.x * blockDim.x + threadIdx.x;
    if (e >= E2) return;
    int se, de;
    if (e < E) { se = ei[e]; de = ei[E + e]; }
    else       { se = e - E; de = se; }
    int pos = atomicAdd(&cursor[de], 1);
    csr_src[row_ptr[de] + pos] = se;
}

// ---- aggregation: wave per node; lane=(e2,c); 16 edges in flight; f16x8 ----
__global__ __launch_bounds__(256) void k_aggregate(const _Float16* __restrict__ hmat,
        const int* __restrict__ row_ptr, const int* __restrict__ csr_src,
        const float* __restrict__ alpha_src, const float* __restrict__ alpha_dst,
        const float* __restrict__ bias, float* __restrict__ outf,
        _Float16* __restrict__ outx, int relu, int nrows) {
    int node = (blockIdx.x * 256 + threadIdx.x) >> 6;
    if (node >= nrows) return;
    int lane = threadIdx.x & 63;
    int e2 = lane >> 5;            // edge-slot half (0/1)
    int c  = lane & 31;            // channel octet: channels c*8..c*8+7
    int head = c >> 3;
    int st = row_ptr[node], en = row_ptr[node + 1];
    int deg = en - st;
    float a_d = alpha_dst[node * 4 + head];
    float acc[8] = {};
    float ssum = 0.f;
    for (int b = 0; b < deg; b += 16) {
        int sn[8];
        #pragma unroll
        for (int j = 0; j < 8; ++j) {
            int e = b + e2 * 8 + j;
            int li = st + (e < deg ? e : deg - 1);
            sn[j] = csr_src[li];
        }
        f16x8 hv[8];
        #pragma unroll
        for (int j = 0; j < 8; ++j)
            hv[j] = *(const f16x8*)&hmat[(size_t)sn[j] * D + c * 8];
        float as[8];
        #pragma unroll
        for (int j = 0; j < 8; ++j) as[j] = alpha_src[sn[j] * 4 + head];
        #pragma unroll
        for (int j = 0; j < 8; ++j) {
            int e = b + e2 * 8 + j;
            float a = as[j] + a_d;
            a = a > 0.f ? a : NEG_SLOPE * a;
            float ex = (e < deg) ? __expf(a) : 0.f;
            ssum += ex;
            #pragma unroll
            for (int k = 0; k < 8; ++k) acc[k] += ex * (float)hv[j][k];
        }
    }
    ssum += __shfl_xor(ssum, 32);
    #pragma unroll
    for (int k = 0; k < 8; ++k) acc[k] += __shfl_xor(acc[k], 32);
    if (e2 == 0) {
        float sinv = 1.f / (ssum + 1e-16f);
        float4 b0 = *(const float4*)&bias[c * 8];
        float4 b1 = *(const float4*)&bias[c * 8 + 4];
        float o[8];
        o[0] = acc[0] * sinv + b0.x; o[1] = acc[1] * sinv + b0.y;
        o[2] = acc[2] * sinv + b0.z; o[3] = acc[3] * sinv + b0.w;
        o[4] = acc[4] * sinv + b1.x; o[5] = acc[5] * sinv + b1.y;
        o[6] = acc[6] * sinv + b1.z; o[7] = acc[7] * sinv + b1.w;
        if (relu) {
            #pragma unroll
            for (int k = 0; k < 8; ++k) o[k] = fmaxf(o[k], 0.f);
        }
        if (outx) {
            f16x8 o8 = {(_Float16)o[0], (_Float16)o[1], (_Float16)o[2], (_Float16)o[3],
                        (_Float16)o[4], (_Float16)o[5], (_Float16)o[6], (_Float16)o[7]};
            *(f16x8*)&outx[(size_t)node * D + c * 8] = o8;
        } else {
            *(float4*)&outf[(size_t)node * D + c * 8] =
                make_float4(o[0], o[1], o[2], o[3]);
            *(float4*)&outf[(size_t)node * D + c * 8 + 4] =
                make_float4(o[4], o[5], o[6], o[7]);
        }
    }
}

extern "C" void kernel_launch(void* const* d_in, const int* in_sizes, int n_in,
                              void* d_out, int out_size, void* d_ws, size_t ws_size,
                              hipStream_t stream) {
    const float* x = (const float*)d_in[0];
    const int* ei = (const int*)d_in[1];
    const int N  = in_sizes[0] / 128;   // 50000
    const int E  = in_sizes[1] / 2;     // 400000
    const int E2 = E + N;               // + self loops

    char* wsp = (char*)d_ws;
    size_t off = 0;
    auto alloc = [&](size_t bytes) -> void* {
        void* p = wsp + off;
        off += (bytes + 255) & ~(size_t)255;
        return p;
    };
    _Float16* bufH  = (_Float16*)alloc((size_t)N * D * 2);     // 25.6 MB
    _Float16* xf16  = (_Float16*)alloc((size_t)N * D * 2);     // 25.6 MB
    _Float16* wf16  = (_Float16*)alloc((size_t)(128 * 256 + 4 * 256 * 256) * 2);
    float* alpha_src = (float*)alloc((size_t)N * H * 4);
    float* alpha_dst = (float*)alloc((size_t)N * H * 4);
    int*   deg       = (int*)alloc((size_t)N * 4);
    int*   incl      = (int*)alloc((size_t)N * 4);
    int*   bsum      = (int*)alloc(256 * 4);
    int*   row_ptr   = (int*)alloc((size_t)(N + 1) * 4);
    int*   cursor    = (int*)alloc((size_t)N * 4);
    int*   csr_src   = (int*)alloc((size_t)E2 * 4);
    (void)ws_size;

    hipMemsetAsync(deg, 0, (size_t)N * 4, stream);
    hipMemsetAsync(cursor, 0, (size_t)N * 4, stream);

    // merged convert: x + all 5 W
    int nx4 = N * 128 / 4;
    int tot4 = nx4 + 128 * 256 / 4 + 4 * (256 * 256 / 4);
    k_cvt_all<<<(tot4 + 255) / 256, 256, 0, stream>>>(
        x, (const float*)d_in[2], (const float*)d_in[6], (const float*)d_in[10],
        (const float*)d_in[14], (const float*)d_in[18], xf16, wf16, nx4);

    // CSR by dst
    int egrid = (E2 + 255) / 256;
    k_deg<<<egrid, 256, 0, stream>>>(ei, E, E2, deg);
    int nb = (N + 255) / 256;
    k_scan_block<<<nb, 256, 0, stream>>>(deg, incl, bsum, N);
    k_scan_bsum<<<1, 256, 0, stream>>>(bsum, nb);
    k_rowptr<<<nb, 256, 0, stream>>>(incl, deg, bsum, row_ptr, N, E2);
    k_scatter<<<egrid, 256, 0, stream>>>(ei, E, E2, row_ptr, cursor, csr_src);

    int ggrid = (N + 63) / 64;
    int agrid = (N + 3) / 4;
    for (int l = 0; l < 5; ++l) {
        const float* as_ = (const float*)d_in[3 + 4 * l];
        const float* ad_ = (const float*)d_in[4 + 4 * l];
        const float* bs_ = (const float*)d_in[5 + 4 * l];
        const _Float16* wl = (l == 0) ? wf16
                           : wf16 + 128 * 256 + (size_t)(l - 1) * 256 * 256;

        if (l == 0)
            k_gemm_mfma<128><<<ggrid, 256, 0, stream>>>(xf16, wl, as_, ad_,
                                                        bufH, alpha_src, alpha_dst, N);
        else
            k_gemm_mfma<256><<<ggrid, 256, 0, stream>>>(xf16, wl, as_, ad_,
                                                        bufH, alpha_src, alpha_dst, N);

        int last = (l == 4);
        k_aggregate<<<agrid, 256, 0, stream>>>(bufH, row_ptr, csr_src,
                                               alpha_src, alpha_dst, bs_,
                                               last ? (float*)d_out : nullptr,
                                               last ? nullptr : xf16,
                                               last ? 0 : 1, N);
    }
}